// Round 11
// baseline (1210.336 us; speedup 1.0000x reference)
//
#include <hip/hip_runtime.h>
#include <cstdint>

// Instant-NGP hash encoding + 2-layer MLP. R11 = R10 + L3-preservation:
//   All non-table traffic is non-temporal (enc NT-stored by encode, NT-loaded
//   by mlp; final out NT-stored) so the 256MB hash tables — exactly L3-sized —
//   stay Infinity-Cache-resident across graph replays. Tables are the ONLY
//   L3-allocating stream.
//   K0 split_w:   W1,W2 fp32 -> hi/lo bf16 pairs in d_ws (196 KB)
//   K1 encode:    hash-gather -> enc fp32 into d_out cols 0..127
//   K2 mlp_mfma:  split-bf16 3-MFMA GEMM (Ah*Bh + Ah*Bl + Al*Bh, fp32 acc)

#define NPTS     524288
#define NLEVELS  16
#define TSIZE    (1u << 19)
#define TMASK    (TSIZE - 1u)
#define APITCH   136      // shorts per LDS row: 128 + 8 pad

typedef float  v4f   __attribute__((ext_vector_type(4)));
typedef float  f32x4 __attribute__((ext_vector_type(4)));
typedef short  s16x8 __attribute__((ext_vector_type(8)));
typedef short  s16x4 __attribute__((ext_vector_type(4)));

// floor(16 * 1.5^l): all fp32-exact integers.
__constant__ float c_res[NLEVELS] = {
    16.f, 24.f, 36.f, 54.f, 81.f, 121.f, 182.f, 273.f,
    410.f, 615.f, 922.f, 1383.f, 2075.f, 3113.f, 4670.f, 7006.f
};

__device__ __forceinline__ uint16_t bf16_rne(float x) {
    uint32_t u = __float_as_uint(x);
    return (uint16_t)((u + 0x7FFFu + ((u >> 16) & 1u)) >> 16);
}
__device__ __forceinline__ void split2(float x, uint16_t& h, uint16_t& l) {
    uint16_t hh = bf16_rne(x);
    float fh = __uint_as_float(((uint32_t)hh) << 16);
    h = hh;
    l = bf16_rne(x - fh);
}

// ---------------- K0: split W1/W2 into hi/lo bf16 in d_ws ----------------
__global__ __launch_bounds__(256)
void split_w(const float* __restrict__ W1, const float* __restrict__ W2,
             uint16_t* __restrict__ ws)
{
    const int i = blockIdx.x * 256 + threadIdx.x;   // 0..49151
    uint16_t h, l;
    if (i < 16384) {
        split2(W1[i], h, l);
        ws[i] = h;
        ws[16384 + i] = l;
    } else {
        const int j = i - 16384;
        split2(W2[j], h, l);
        ws[32768 + j] = h;
        ws[65536 + j] = l;
    }
}

// ---------------- K1: hash encode -> out[p*256 + l*8 .. +7] ----------------
__global__ __launch_bounds__(256, 4)
void ngp_encode(const float* __restrict__ z,
                const float* __restrict__ tables,
                float* __restrict__ out)
{
    const int id = blockIdx.x * 256 + threadIdx.x;
    const int p  = id >> 4;
    const int l  = id & 15;

    const float z0 = z[p * 3 + 0];
    const float z1 = z[p * 3 + 1];
    const float z2 = z[p * 3 + 2];

    const float res = c_res[l];
    const float xs0 = z0 * res, xs1 = z1 * res, xs2 = z2 * res;
    const float f0 = floorf(xs0), f1 = floorf(xs1), f2 = floorf(xs2);
    const float w0 = xs0 - f0, w1 = xs1 - f1, w2 = xs2 - f2;
    const uint32_t x0 = (uint32_t)f0;
    const uint32_t x1 = (uint32_t)f1;
    const uint32_t x2 = (uint32_t)f2;

    uint32_t idxs[8];
    #pragma unroll
    for (int c = 0; c < 8; ++c) {
        const uint32_t hx = (x0 + ((c >> 2) & 1u)) * 1u;
        const uint32_t hy = (x1 + ((c >> 1) & 1u)) * 2654435761u;
        const uint32_t hz = (x2 + (c & 1u)) * 805459861u;
        idxs[c] = (hx ^ hy ^ hz) & TMASK;
    }

    const float* tab = tables + (size_t)l * (size_t)(TSIZE * 8);

    float a0 = 0.f, a1 = 0.f, a2 = 0.f, a3 = 0.f;
    float a4 = 0.f, a5 = 0.f, a6 = 0.f, a7 = 0.f;

    #pragma unroll
    for (int half = 0; half < 2; ++half) {
        float4 fa[4], fb[4];
        #pragma unroll
        for (int c = 0; c < 4; ++c) {
            const float4* fp = reinterpret_cast<const float4*>(
                tab + ((size_t)idxs[half * 4 + c] << 3));
            fa[c] = fp[0];
            fb[c] = fp[1];
        }
        #pragma unroll
        for (int c = 0; c < 4; ++c) {
            const int cc = half * 4 + c;
            const float cwx = ((cc >> 2) & 1) ? w0 : (1.0f - w0);
            const float cwy = ((cc >> 1) & 1) ? w1 : (1.0f - w1);
            const float cwz = (cc & 1) ? w2 : (1.0f - w2);
            const float cw = (cwx * cwy) * cwz;    // same order as reference prod(-1)
            a0 = fmaf(cw, fa[c].x, a0);
            a1 = fmaf(cw, fa[c].y, a1);
            a2 = fmaf(cw, fa[c].z, a2);
            a3 = fmaf(cw, fa[c].w, a3);
            a4 = fmaf(cw, fb[c].x, a4);
            a5 = fmaf(cw, fb[c].y, a5);
            a6 = fmaf(cw, fb[c].z, a6);
            a7 = fmaf(cw, fb[c].w, a7);
        }
    }

    // NT: enc is consumed once by K2 -> don't let it evict tables from L3
    float* op = out + (size_t)p * 256 + l * 8;
    v4f s;
    s.x = a0; s.y = a1; s.z = a2; s.w = a3;
    __builtin_nontemporal_store(s, reinterpret_cast<v4f*>(op));
    s.x = a4; s.y = a5; s.z = a6; s.w = a7;
    __builtin_nontemporal_store(s, reinterpret_cast<v4f*>(op + 4));
}

// ---------------- K2: split-bf16 MFMA MLP ----------------
__global__ __launch_bounds__(256, 2)
void ngp_mlp_mfma(const uint16_t* __restrict__ ws,
                  const float* __restrict__ b1,
                  const float* __restrict__ b2,
                  float* out)
{
    __shared__ short Ah[64 * APITCH];
    __shared__ short Al[64 * APITCH];
    __shared__ short Hh[64 * APITCH];
    __shared__ short Hl[64 * APITCH];

    const int t     = threadIdx.x;
    const int lane  = t & 63;
    const int w     = t >> 6;
    const int lrow  = lane & 15;
    const int kgrp  = lane >> 4;
    const int pbase = blockIdx.x * 64;

    const uint16_t* W1h = ws;
    const uint16_t* W1l = ws + 16384;
    const uint16_t* W2h = ws + 32768;
    const uint16_t* W2l = ws + 65536;

    // ---- stage enc (NT loads -> no L3 pollution) -> split bf16 LDS ----
    #pragma unroll
    for (int i = 0; i < 8; ++i) {
        const int slot = t + i * 256;
        const int p    = slot >> 5;
        const int c4   = slot & 31;
        const v4f v = __builtin_nontemporal_load(
            reinterpret_cast<const v4f*>(out + (size_t)(pbase + p) * 256 + c4 * 4));
        uint16_t h0, l0, h1, l1, h2, l2, h3, l3;
        split2(v.x, h0, l0); split2(v.y, h1, l1);
        split2(v.z, h2, l2); split2(v.w, h3, l3);
        s16x4 sh = { (short)h0, (short)h1, (short)h2, (short)h3 };
        s16x4 sl = { (short)l0, (short)l1, (short)l2, (short)l3 };
        *reinterpret_cast<s16x4*>(&Ah[p * APITCH + c4 * 4]) = sh;
        *reinterpret_cast<s16x4*>(&Al[p * APITCH + c4 * 4]) = sl;
    }
    __syncthreads();

    // ---- layer 1: [64x128] @ W1^T, wave cols = [w*32, w*32+32) ----
    {
        const int nb = w * 32;
        f32x4 acc[4][2];
        #pragma unroll
        for (int mi = 0; mi < 4; ++mi)
            #pragma unroll
            for (int ni = 0; ni < 2; ++ni)
                acc[mi][ni] = (f32x4){ 0.f, 0.f, 0.f, 0.f };

        #pragma unroll
        for (int kc = 0; kc < 4; ++kc) {
            const int koff = kc * 32 + kgrp * 8;
            s16x8 ah[4], al[4];
            #pragma unroll
            for (int mi = 0; mi < 4; ++mi) {
                const int row = mi * 16 + lrow;
                ah[mi] = *reinterpret_cast<const s16x8*>(&Ah[row * APITCH + koff]);
                al[mi] = *reinterpret_cast<const s16x8*>(&Al[row * APITCH + koff]);
            }
            s16x8 bh[2], bl[2];
            #pragma unroll
            for (int ni = 0; ni < 2; ++ni) {
                const int col = nb + ni * 16 + lrow;
                bh[ni] = *reinterpret_cast<const s16x8*>(&W1h[col * 128 + koff]);
                bl[ni] = *reinterpret_cast<const s16x8*>(&W1l[col * 128 + koff]);
            }
            #pragma unroll
            for (int mi = 0; mi < 4; ++mi)
                #pragma unroll
                for (int ni = 0; ni < 2; ++ni) {
                    acc[mi][ni] = __builtin_amdgcn_mfma_f32_16x16x32_bf16(
                        ah[mi], bh[ni], acc[mi][ni], 0, 0, 0);
                    acc[mi][ni] = __builtin_amdgcn_mfma_f32_16x16x32_bf16(
                        ah[mi], bl[ni], acc[mi][ni], 0, 0, 0);
                    acc[mi][ni] = __builtin_amdgcn_mfma_f32_16x16x32_bf16(
                        al[mi], bh[ni], acc[mi][ni], 0, 0, 0);
                }
        }

        #pragma unroll
        for (int mi = 0; mi < 4; ++mi)
            #pragma unroll
            for (int ni = 0; ni < 2; ++ni) {
                const int col = nb + ni * 16 + lrow;
                const float bj = b1[col];
                #pragma unroll
                for (int r = 0; r < 4; ++r) {
                    const int row = mi * 16 + kgrp * 4 + r;
                    float v = acc[mi][ni][r] + bj;
                    v = (v >= 0.f) ? v : 0.01f * v;
                    uint16_t h, l;
                    split2(v, h, l);
                    Hh[row * APITCH + col] = (short)h;
                    Hl[row * APITCH + col] = (short)l;
                }
            }
    }
    __syncthreads();

    // ---- layer 2: [64x128] @ W2^T, wave cols = [w*64, w*64+64) ----
    #pragma unroll
    for (int pass = 0; pass < 2; ++pass) {
        const int nb = w * 64 + pass * 32;
        f32x4 acc[4][2];
        #pragma unroll
        for (int mi = 0; mi < 4; ++mi)
            #pragma unroll
            for (int ni = 0; ni < 2; ++ni)
                acc[mi][ni] = (f32x4){ 0.f, 0.f, 0.f, 0.f };

        #pragma unroll
        for (int kc = 0; kc < 4; ++kc) {
            const int koff = kc * 32 + kgrp * 8;
            s16x8 ah[4], al[4];
            #pragma unroll
            for (int mi = 0; mi < 4; ++mi) {
                const int row = mi * 16 + lrow;
                ah[mi] = *reinterpret_cast<const s16x8*>(&Hh[row * APITCH + koff]);
                al[mi] = *reinterpret_cast<const s16x8*>(&Hl[row * APITCH + koff]);
            }
            s16x8 bh[2], bl[2];
            #pragma unroll
            for (int ni = 0; ni < 2; ++ni) {
                const int col = nb + ni * 16 + lrow;
                bh[ni] = *reinterpret_cast<const s16x8*>(&W2h[col * 128 + koff]);
                bl[ni] = *reinterpret_cast<const s16x8*>(&W2l[col * 128 + koff]);
            }
            #pragma unroll
            for (int mi = 0; mi < 4; ++mi)
                #pragma unroll
                for (int ni = 0; ni < 2; ++ni) {
                    acc[mi][ni] = __builtin_amdgcn_mfma_f32_16x16x32_bf16(
                        ah[mi], bh[ni], acc[mi][ni], 0, 0, 0);
                    acc[mi][ni] = __builtin_amdgcn_mfma_f32_16x16x32_bf16(
                        ah[mi], bl[ni], acc[mi][ni], 0, 0, 0);
                    acc[mi][ni] = __builtin_amdgcn_mfma_f32_16x16x32_bf16(
                        al[mi], bh[ni], acc[mi][ni], 0, 0, 0);
                }
        }

        #pragma unroll
        for (int mi = 0; mi < 4; ++mi)
            #pragma unroll
            for (int ni = 0; ni < 2; ++ni) {
                const int col = nb + ni * 16 + lrow;
                const float bj = b2[col];
                #pragma unroll
                for (int r = 0; r < 4; ++r) {
                    const int row = mi * 16 + kgrp * 4 + r;
                    __builtin_nontemporal_store(
                        acc[mi][ni][r] + bj,
                        out + (size_t)(pbase + row) * 256 + col);
                }
            }
    }
}

// ---------------- fallback fp32 VALU MLP (known-good) ----------------
#define PTS_BLK2 32
#define PITCH2   132
__global__ __launch_bounds__(256, 4)
void ngp_mlp_valu(const float* __restrict__ W1, const float* __restrict__ b1,
                  const float* __restrict__ W2, const float* __restrict__ b2,
                  float* out)
{
    __shared__ __align__(16) float buf[PTS_BLK2][PITCH2];
    __shared__ __align__(16) float sout[PTS_BLK2][PITCH2];

    const int t     = threadIdx.x;
    const int pbase = blockIdx.x * PTS_BLK2;

    #pragma unroll
    for (int i = 0; i < 4; ++i) {
        const int idx = t + i * 256;
        const int p = idx >> 5, c4 = idx & 31;
        *reinterpret_cast<float4*>(&buf[p][c4 * 4]) =
            *reinterpret_cast<const float4*>(out + (size_t)(pbase + p) * 256 + c4 * 4);
    }
    __syncthreads();

    const int px = t & 15, cy = t >> 4, colb = cy * 8;

    float h0[8], h1[8];
    {
        float a0[8], a1[8];
        #pragma unroll
        for (int j = 0; j < 8; ++j) { a0[j] = 0.f; a1[j] = 0.f; }
        #pragma unroll 2
        for (int k = 0; k < 128; k += 4) {
            const float4 e0 = *reinterpret_cast<const float4*>(&buf[px][k]);
            const float4 e1 = *reinterpret_cast<const float4*>(&buf[px + 16][k]);
            #pragma unroll
            for (int j = 0; j < 8; ++j) {
                const float4 wv = *reinterpret_cast<const float4*>(&W1[(size_t)(colb + j) * 128 + k]);
                a0[j] = fmaf(e0.x, wv.x, a0[j]); a0[j] = fmaf(e0.y, wv.y, a0[j]);
                a0[j] = fmaf(e0.z, wv.z, a0[j]); a0[j] = fmaf(e0.w, wv.w, a0[j]);
                a1[j] = fmaf(e1.x, wv.x, a1[j]); a1[j] = fmaf(e1.y, wv.y, a1[j]);
                a1[j] = fmaf(e1.z, wv.z, a1[j]); a1[j] = fmaf(e1.w, wv.w, a1[j]);
            }
        }
        #pragma unroll
        for (int j = 0; j < 8; ++j) {
            const float bj = b1[colb + j];
            float v0 = a0[j] + bj, v1 = a1[j] + bj;
            h0[j] = (v0 >= 0.f) ? v0 : 0.01f * v0;
            h1[j] = (v1 >= 0.f) ? v1 : 0.01f * v1;
        }
    }
    __syncthreads();
    *reinterpret_cast<float4*>(&buf[px][colb])          = make_float4(h0[0], h0[1], h0[2], h0[3]);
    *reinterpret_cast<float4*>(&buf[px][colb + 4])      = make_float4(h0[4], h0[5], h0[6], h0[7]);
    *reinterpret_cast<float4*>(&buf[px + 16][colb])     = make_float4(h1[0], h1[1], h1[2], h1[3]);
    *reinterpret_cast<float4*>(&buf[px + 16][colb + 4]) = make_float4(h1[4], h1[5], h1[6], h1[7]);
    __syncthreads();

    #pragma unroll
    for (int half = 0; half < 2; ++half) {
        float c0[8], c1[8];
        #pragma unroll
        for (int j = 0; j < 8; ++j) { c0[j] = 0.f; c1[j] = 0.f; }
        const int orow = half * 128 + colb;
        #pragma unroll 2
        for (int k = 0; k < 128; k += 4) {
            const float4 g0 = *reinterpret_cast<const float4*>(&buf[px][k]);
            const float4 g1 = *reinterpret_cast<const float4*>(&buf[px + 16][k]);
            #pragma unroll
            for (int j = 0; j < 8; ++j) {
                const float4 wv = *reinterpret_cast<const float4*>(&W2[(size_t)(orow + j) * 128 + k]);
                c0[j] = fmaf(g0.x, wv.x, c0[j]); c0[j] = fmaf(g0.y, wv.y, c0[j]);
                c0[j] = fmaf(g0.z, wv.z, c0[j]); c0[j] = fmaf(g0.w, wv.w, c0[j]);
                c1[j] = fmaf(g1.x, wv.x, c1[j]); c1[j] = fmaf(g1.y, wv.y, c1[j]);
                c1[j] = fmaf(g1.z, wv.z, c1[j]); c1[j] = fmaf(g1.w, wv.w, c1[j]);
            }
        }
        #pragma unroll
        for (int j = 0; j < 8; ++j) { c0[j] += b2[orow + j]; c1[j] += b2[orow + j]; }
        *reinterpret_cast<float4*>(&sout[px][colb])          = make_float4(c0[0], c0[1], c0[2], c0[3]);
        *reinterpret_cast<float4*>(&sout[px][colb + 4])      = make_float4(c0[4], c0[5], c0[6], c0[7]);
        *reinterpret_cast<float4*>(&sout[px + 16][colb])     = make_float4(c1[0], c1[1], c1[2], c1[3]);
        *reinterpret_cast<float4*>(&sout[px + 16][colb + 4]) = make_float4(c1[4], c1[5], c1[6], c1[7]);
        __syncthreads();
        #pragma unroll
        for (int i = 0; i < 4; ++i) {
            const int idx = t + i * 256;
            const int p = idx >> 5, c4 = idx & 31;
            const float4 v = *reinterpret_cast<const float4*>(&sout[p][c4 * 4]);
            v4f s; s.x = v.x; s.y = v.y; s.z = v.z; s.w = v.w;
            __builtin_nontemporal_store(
                s, reinterpret_cast<v4f*>(out + (size_t)(pbase + p) * 256 + half * 128 + c4 * 4));
        }
        __syncthreads();
    }
}

extern "C" void kernel_launch(void* const* d_in, const int* in_sizes, int n_in,
                              void* d_out, int out_size, void* d_ws, size_t ws_size,
                              hipStream_t stream) {
    (void)in_sizes; (void)n_in; (void)out_size;

    const float* z      = (const float*)d_in[0];
    const float* tables = (const float*)d_in[1];
    const float* W1     = (const float*)d_in[2];
    const float* b1     = (const float*)d_in[3];
    const float* W2     = (const float*)d_in[4];
    const float* b2     = (const float*)d_in[5];
    float* out          = (float*)d_out;

    ngp_encode<<<dim3((NPTS * 16) / 256), dim3(256), 0, stream>>>(z, tables, out);

    if (ws_size >= 196608) {
        split_w<<<dim3(192), dim3(256), 0, stream>>>(W1, W2, (uint16_t*)d_ws);
        ngp_mlp_mfma<<<dim3(NPTS / 64), dim3(256), 0, stream>>>(
            (const uint16_t*)d_ws, b1, b2, out);
    } else {
        ngp_mlp_valu<<<dim3(NPTS / PTS_BLK2), dim3(256), 0, stream>>>(
            W1, b1, W2, b2, out);
    }
}

// Round 15
// 1161.792 us; speedup vs baseline: 1.0418x; 1.0418x over previous
//
#include <hip/hip_runtime.h>
#include <cstdint>

// Instant-NGP hash encoding + 2-layer MLP. R15 = proven R10 pipeline
// (encode -> split-bf16 3-MFMA MLP, passed at 1197us) with ONE change:
// encode blocks are level-PAIR-partitioned and XCD-pinned.
//   Block = pair j (levels 2j,2j+1) x 128 points; j = blockIdx%8 -> XCD j
//   under round-robin dispatch. Each XCD's 4MB L2 then serves only 2 levels
//   (<=32MB) instead of all 16 (~200MB) -> L2 retention on fine-level
//   gathers. Lanes (2i,2i+1) write one full 64B line per point (no RMW).
// MLP path byte-identical to R10's (proven).

#define NPTS     524288
#define NLEVELS  16
#define TSIZE    (1u << 19)
#define TMASK    (TSIZE - 1u)
#define APITCH   136      // shorts per LDS row: 128 + 8 pad

typedef float  v4f   __attribute__((ext_vector_type(4)));
typedef float  f32x4 __attribute__((ext_vector_type(4)));
typedef short  s16x8 __attribute__((ext_vector_type(8)));
typedef short  s16x4 __attribute__((ext_vector_type(4)));

// floor(16 * 1.5^l): all fp32-exact integers.
__constant__ float c_res[NLEVELS] = {
    16.f, 24.f, 36.f, 54.f, 81.f, 121.f, 182.f, 273.f,
    410.f, 615.f, 922.f, 1383.f, 2075.f, 3113.f, 4670.f, 7006.f
};

__device__ __forceinline__ uint16_t bf16_rne(float x) {
    uint32_t u = __float_as_uint(x);
    return (uint16_t)((u + 0x7FFFu + ((u >> 16) & 1u)) >> 16);
}
__device__ __forceinline__ void split2(float x, uint16_t& h, uint16_t& l) {
    uint16_t hh = bf16_rne(x);
    float fh = __uint_as_float(((uint32_t)hh) << 16);
    h = hh;
    l = bf16_rne(x - fh);
}

// ---------------- K0: split W1/W2 into hi/lo bf16 in d_ws ----------------
__global__ __launch_bounds__(256)
void split_w(const float* __restrict__ W1, const float* __restrict__ W2,
             uint16_t* __restrict__ ws)
{
    const int i = blockIdx.x * 256 + threadIdx.x;   // 0..49151
    uint16_t h, l;
    if (i < 16384) {
        split2(W1[i], h, l);
        ws[i] = h;
        ws[16384 + i] = l;
    } else {
        const int j = i - 16384;
        split2(W2[j], h, l);
        ws[32768 + j] = h;
        ws[65536 + j] = l;
    }
}

// ---------------- K1: hash encode, level-pair XCD-pinned ----------------
// Block: pair j = blockIdx%8 (levels 2j, 2j+1), points m*128..m*128+127.
// Thread: l = 2j + (t&1), p = m*128 + (t>>1).
// Writes out[p*256 + l*8 .. +7]; lanes (2i,2i+1) cover one 64B line.
__global__ __launch_bounds__(256, 4)
void ngp_encode(const float* __restrict__ z,
                const float* __restrict__ tables,
                float* __restrict__ out)
{
    const int j = blockIdx.x & 7;
    const int m = blockIdx.x >> 3;
    const int t = threadIdx.x;
    const int l = 2 * j + (t & 1);
    const int p = m * 128 + (t >> 1);

    const float z0 = z[p * 3 + 0];
    const float z1 = z[p * 3 + 1];
    const float z2 = z[p * 3 + 2];

    const float res = c_res[l];
    const float xs0 = z0 * res, xs1 = z1 * res, xs2 = z2 * res;
    const float f0 = floorf(xs0), f1 = floorf(xs1), f2 = floorf(xs2);
    const float w0 = xs0 - f0, w1 = xs1 - f1, w2 = xs2 - f2;
    const uint32_t x0 = (uint32_t)f0;
    const uint32_t x1 = (uint32_t)f1;
    const uint32_t x2 = (uint32_t)f2;

    uint32_t idxs[8];
    #pragma unroll
    for (int c = 0; c < 8; ++c) {
        const uint32_t hx = (x0 + ((c >> 2) & 1u)) * 1u;
        const uint32_t hy = (x1 + ((c >> 1) & 1u)) * 2654435761u;
        const uint32_t hz = (x2 + (c & 1u)) * 805459861u;
        idxs[c] = (hx ^ hy ^ hz) & TMASK;
    }

    const float* tab = tables + (size_t)l * (size_t)(TSIZE * 8);

    float a0 = 0.f, a1 = 0.f, a2 = 0.f, a3 = 0.f;
    float a4 = 0.f, a5 = 0.f, a6 = 0.f, a7 = 0.f;

    #pragma unroll
    for (int half = 0; half < 2; ++half) {
        float4 fa[4], fb[4];
        #pragma unroll
        for (int c = 0; c < 4; ++c) {
            const float4* fp = reinterpret_cast<const float4*>(
                tab + ((size_t)idxs[half * 4 + c] << 3));
            fa[c] = fp[0];
            fb[c] = fp[1];
        }
        #pragma unroll
        for (int c = 0; c < 4; ++c) {
            const int cc = half * 4 + c;
            const float cwx = ((cc >> 2) & 1) ? w0 : (1.0f - w0);
            const float cwy = ((cc >> 1) & 1) ? w1 : (1.0f - w1);
            const float cwz = (cc & 1) ? w2 : (1.0f - w2);
            const float cw = (cwx * cwy) * cwz;    // same order as reference prod(-1)
            a0 = fmaf(cw, fa[c].x, a0);
            a1 = fmaf(cw, fa[c].y, a1);
            a2 = fmaf(cw, fa[c].z, a2);
            a3 = fmaf(cw, fa[c].w, a3);
            a4 = fmaf(cw, fb[c].x, a4);
            a5 = fmaf(cw, fb[c].y, a5);
            a6 = fmaf(cw, fb[c].z, a6);
            a7 = fmaf(cw, fb[c].w, a7);
        }
    }

    float* op = out + (size_t)p * 256 + l * 8;
    *reinterpret_cast<float4*>(op)     = make_float4(a0, a1, a2, a3);
    *reinterpret_cast<float4*>(op + 4) = make_float4(a4, a5, a6, a7);
}

// ---------------- K2: split-bf16 MFMA MLP (verbatim from R10, proven) ----------------
__global__ __launch_bounds__(256, 2)
void ngp_mlp_mfma(const uint16_t* __restrict__ ws,
                  const float* __restrict__ b1,
                  const float* __restrict__ b2,
                  float* out)
{
    __shared__ short Ah[64 * APITCH];
    __shared__ short Al[64 * APITCH];
    __shared__ short Hh[64 * APITCH];
    __shared__ short Hl[64 * APITCH];

    const int t     = threadIdx.x;
    const int lane  = t & 63;
    const int w     = t >> 6;
    const int lrow  = lane & 15;
    const int kgrp  = lane >> 4;
    const int pbase = blockIdx.x * 64;

    const uint16_t* W1h = ws;
    const uint16_t* W1l = ws + 16384;
    const uint16_t* W2h = ws + 32768;
    const uint16_t* W2l = ws + 65536;

    // ---- stage enc (fp32, d_out cols 0..127) -> split bf16 LDS ----
    #pragma unroll
    for (int i = 0; i < 8; ++i) {
        const int slot = t + i * 256;
        const int p    = slot >> 5;
        const int c4   = slot & 31;
        const float4 v = *reinterpret_cast<const float4*>(
            out + (size_t)(pbase + p) * 256 + c4 * 4);
        uint16_t h0, l0, h1, l1, h2, l2, h3, l3;
        split2(v.x, h0, l0); split2(v.y, h1, l1);
        split2(v.z, h2, l2); split2(v.w, h3, l3);
        s16x4 sh = { (short)h0, (short)h1, (short)h2, (short)h3 };
        s16x4 sl = { (short)l0, (short)l1, (short)l2, (short)l3 };
        *reinterpret_cast<s16x4*>(&Ah[p * APITCH + c4 * 4]) = sh;
        *reinterpret_cast<s16x4*>(&Al[p * APITCH + c4 * 4]) = sl;
    }
    __syncthreads();

    // ---- layer 1: [64x128] @ W1^T, wave cols = [w*32, w*32+32) ----
    {
        const int nb = w * 32;
        f32x4 acc[4][2];
        #pragma unroll
        for (int mi = 0; mi < 4; ++mi)
            #pragma unroll
            for (int ni = 0; ni < 2; ++ni)
                acc[mi][ni] = (f32x4){ 0.f, 0.f, 0.f, 0.f };

        #pragma unroll
        for (int kc = 0; kc < 4; ++kc) {
            const int koff = kc * 32 + kgrp * 8;
            s16x8 ah[4], al[4];
            #pragma unroll
            for (int mi = 0; mi < 4; ++mi) {
                const int row = mi * 16 + lrow;
                ah[mi] = *reinterpret_cast<const s16x8*>(&Ah[row * APITCH + koff]);
                al[mi] = *reinterpret_cast<const s16x8*>(&Al[row * APITCH + koff]);
            }
            s16x8 bh[2], bl[2];
            #pragma unroll
            for (int ni = 0; ni < 2; ++ni) {
                const int col = nb + ni * 16 + lrow;
                bh[ni] = *reinterpret_cast<const s16x8*>(&W1h[col * 128 + koff]);
                bl[ni] = *reinterpret_cast<const s16x8*>(&W1l[col * 128 + koff]);
            }
            #pragma unroll
            for (int mi = 0; mi < 4; ++mi)
                #pragma unroll
                for (int ni = 0; ni < 2; ++ni) {
                    acc[mi][ni] = __builtin_amdgcn_mfma_f32_16x16x32_bf16(
                        ah[mi], bh[ni], acc[mi][ni], 0, 0, 0);
                    acc[mi][ni] = __builtin_amdgcn_mfma_f32_16x16x32_bf16(
                        ah[mi], bl[ni], acc[mi][ni], 0, 0, 0);
                    acc[mi][ni] = __builtin_amdgcn_mfma_f32_16x16x32_bf16(
                        al[mi], bh[ni], acc[mi][ni], 0, 0, 0);
                }
        }

        // bias + LeakyReLU, split to bf16 hi/lo hidden
        #pragma unroll
        for (int mi = 0; mi < 4; ++mi)
            #pragma unroll
            for (int ni = 0; ni < 2; ++ni) {
                const int col = nb + ni * 16 + lrow;
                const float bj = b1[col];
                #pragma unroll
                for (int r = 0; r < 4; ++r) {
                    const int row = mi * 16 + kgrp * 4 + r;
                    float v = acc[mi][ni][r] + bj;
                    v = (v >= 0.f) ? v : 0.01f * v;
                    uint16_t h, l;
                    split2(v, h, l);
                    Hh[row * APITCH + col] = (short)h;
                    Hl[row * APITCH + col] = (short)l;
                }
            }
    }
    __syncthreads();

    // ---- layer 2: [64x128] @ W2^T, wave cols = [w*64, w*64+64) ----
    #pragma unroll
    for (int pass = 0; pass < 2; ++pass) {
        const int nb = w * 64 + pass * 32;
        f32x4 acc[4][2];
        #pragma unroll
        for (int mi = 0; mi < 4; ++mi)
            #pragma unroll
            for (int ni = 0; ni < 2; ++ni)
                acc[mi][ni] = (f32x4){ 0.f, 0.f, 0.f, 0.f };

        #pragma unroll
        for (int kc = 0; kc < 4; ++kc) {
            const int koff = kc * 32 + kgrp * 8;
            s16x8 ah[4], al[4];
            #pragma unroll
            for (int mi = 0; mi < 4; ++mi) {
                const int row = mi * 16 + lrow;
                ah[mi] = *reinterpret_cast<const s16x8*>(&Hh[row * APITCH + koff]);
                al[mi] = *reinterpret_cast<const s16x8*>(&Hl[row * APITCH + koff]);
            }
            s16x8 bh[2], bl[2];
            #pragma unroll
            for (int ni = 0; ni < 2; ++ni) {
                const int col = nb + ni * 16 + lrow;
                bh[ni] = *reinterpret_cast<const s16x8*>(&W2h[col * 128 + koff]);
                bl[ni] = *reinterpret_cast<const s16x8*>(&W2l[col * 128 + koff]);
            }
            #pragma unroll
            for (int mi = 0; mi < 4; ++mi)
                #pragma unroll
                for (int ni = 0; ni < 2; ++ni) {
                    acc[mi][ni] = __builtin_amdgcn_mfma_f32_16x16x32_bf16(
                        ah[mi], bh[ni], acc[mi][ni], 0, 0, 0);
                    acc[mi][ni] = __builtin_amdgcn_mfma_f32_16x16x32_bf16(
                        ah[mi], bl[ni], acc[mi][ni], 0, 0, 0);
                    acc[mi][ni] = __builtin_amdgcn_mfma_f32_16x16x32_bf16(
                        al[mi], bh[ni], acc[mi][ni], 0, 0, 0);
                }
        }

        #pragma unroll
        for (int mi = 0; mi < 4; ++mi)
            #pragma unroll
            for (int ni = 0; ni < 2; ++ni) {
                const int col = nb + ni * 16 + lrow;
                const float bj = b2[col];
                #pragma unroll
                for (int r = 0; r < 4; ++r) {
                    const int row = mi * 16 + kgrp * 4 + r;
                    __builtin_nontemporal_store(
                        acc[mi][ni][r] + bj,
                        out + (size_t)(pbase + row) * 256 + col);
                }
            }
    }
}

// ---------------- fallback fp32 VALU MLP (known-good) ----------------
#define PTS_BLK2 32
#define PITCH2   132
__global__ __launch_bounds__(256, 4)
void ngp_mlp_valu(const float* __restrict__ W1, const float* __restrict__ b1,
                  const float* __restrict__ W2, const float* __restrict__ b2,
                  float* out)
{
    __shared__ __align__(16) float buf[PTS_BLK2][PITCH2];
    __shared__ __align__(16) float sout[PTS_BLK2][PITCH2];

    const int t     = threadIdx.x;
    const int pbase = blockIdx.x * PTS_BLK2;

    #pragma unroll
    for (int i = 0; i < 4; ++i) {
        const int idx = t + i * 256;
        const int p = idx >> 5, c4 = idx & 31;
        *reinterpret_cast<float4*>(&buf[p][c4 * 4]) =
            *reinterpret_cast<const float4*>(out + (size_t)(pbase + p) * 256 + c4 * 4);
    }
    __syncthreads();

    const int px = t & 15, cy = t >> 4, colb = cy * 8;

    float h0[8], h1[8];
    {
        float a0[8], a1[8];
        #pragma unroll
        for (int j = 0; j < 8; ++j) { a0[j] = 0.f; a1[j] = 0.f; }
        #pragma unroll 2
        for (int k = 0; k < 128; k += 4) {
            const float4 e0 = *reinterpret_cast<const float4*>(&buf[px][k]);
            const float4 e1 = *reinterpret_cast<const float4*>(&buf[px + 16][k]);
            #pragma unroll
            for (int j = 0; j < 8; ++j) {
                const float4 wv = *reinterpret_cast<const float4*>(&W1[(size_t)(colb + j) * 128 + k]);
                a0[j] = fmaf(e0.x, wv.x, a0[j]); a0[j] = fmaf(e0.y, wv.y, a0[j]);
                a0[j] = fmaf(e0.z, wv.z, a0[j]); a0[j] = fmaf(e0.w, wv.w, a0[j]);
                a1[j] = fmaf(e1.x, wv.x, a1[j]); a1[j] = fmaf(e1.y, wv.y, a1[j]);
                a1[j] = fmaf(e1.z, wv.z, a1[j]); a1[j] = fmaf(e1.w, wv.w, a1[j]);
            }
        }
        #pragma unroll
        for (int j = 0; j < 8; ++j) {
            const float bj = b1[colb + j];
            float v0 = a0[j] + bj, v1 = a1[j] + bj;
            h0[j] = (v0 >= 0.f) ? v0 : 0.01f * v0;
            h1[j] = (v1 >= 0.f) ? v1 : 0.01f * v1;
        }
    }
    __syncthreads();
    *reinterpret_cast<float4*>(&buf[px][colb])          = make_float4(h0[0], h0[1], h0[2], h0[3]);
    *reinterpret_cast<float4*>(&buf[px][colb + 4])      = make_float4(h0[4], h0[5], h0[6], h0[7]);
    *reinterpret_cast<float4*>(&buf[px + 16][colb])     = make_float4(h1[0], h1[1], h1[2], h1[3]);
    *reinterpret_cast<float4*>(&buf[px + 16][colb + 4]) = make_float4(h1[4], h1[5], h1[6], h1[7]);
    __syncthreads();

    #pragma unroll
    for (int half = 0; half < 2; ++half) {
        float c0[8], c1[8];
        #pragma unroll
        for (int j = 0; j < 8; ++j) { c0[j] = 0.f; c1[j] = 0.f; }
        const int orow = half * 128 + colb;
        #pragma unroll 2
        for (int k = 0; k < 128; k += 4) {
            const float4 g0 = *reinterpret_cast<const float4*>(&buf[px][k]);
            const float4 g1 = *reinterpret_cast<const float4*>(&buf[px + 16][k]);
            #pragma unroll
            for (int j = 0; j < 8; ++j) {
                const float4 wv = *reinterpret_cast<const float4*>(&W2[(size_t)(orow + j) * 128 + k]);
                c0[j] = fmaf(g0.x, wv.x, c0[j]); c0[j] = fmaf(g0.y, wv.y, c0[j]);
                c0[j] = fmaf(g0.z, wv.z, c0[j]); c0[j] = fmaf(g0.w, wv.w, c0[j]);
                c1[j] = fmaf(g1.x, wv.x, c1[j]); c1[j] = fmaf(g1.y, wv.y, c1[j]);
                c1[j] = fmaf(g1.z, wv.z, c1[j]); c1[j] = fmaf(g1.w, wv.w, c1[j]);
            }
        }
        #pragma unroll
        for (int j = 0; j < 8; ++j) { c0[j] += b2[orow + j]; c1[j] += b2[orow + j]; }
        *reinterpret_cast<float4*>(&sout[px][colb])          = make_float4(c0[0], c0[1], c0[2], c0[3]);
        *reinterpret_cast<float4*>(&sout[px][colb + 4])      = make_float4(c0[4], c0[5], c0[6], c0[7]);
        *reinterpret_cast<float4*>(&sout[px + 16][colb])     = make_float4(c1[0], c1[1], c1[2], c1[3]);
        *reinterpret_cast<float4*>(&sout[px + 16][colb + 4]) = make_float4(c1[4], c1[5], c1[6], c1[7]);
        __syncthreads();
        #pragma unroll
        for (int i = 0; i < 4; ++i) {
            const int idx = t + i * 256;
            const int p = idx >> 5, c4 = idx & 31;
            const float4 v = *reinterpret_cast<const float4*>(&sout[p][c4 * 4]);
            v4f s; s.x = v.x; s.y = v.y; s.z = v.z; s.w = v.w;
            __builtin_nontemporal_store(
                s, reinterpret_cast<v4f*>(out + (size_t)(pbase + p) * 256 + half * 128 + c4 * 4));
        }
        __syncthreads();
    }
}

extern "C" void kernel_launch(void* const* d_in, const int* in_sizes, int n_in,
                              void* d_out, int out_size, void* d_ws, size_t ws_size,
                              hipStream_t stream) {
    (void)in_sizes; (void)n_in; (void)out_size;

    const float* z      = (const float*)d_in[0];
    const float* tables = (const float*)d_in[1];
    const float* W1     = (const float*)d_in[2];
    const float* b1     = (const float*)d_in[3];
    const float* W2     = (const float*)d_in[4];
    const float* b2     = (const float*)d_in[5];
    float* out          = (float*)d_out;

    // encode: 8 pairs x (524288/128) chunks = 32768 blocks; pair = blockIdx%8
    ngp_encode<<<dim3((NPTS / 128) * 8), dim3(256), 0, stream>>>(z, tables, out);

    if (ws_size >= 196608) {
        split_w<<<dim3(192), dim3(256), 0, stream>>>(W1, W2, (uint16_t*)d_ws);
        ngp_mlp_mfma<<<dim3(NPTS / 64), dim3(256), 0, stream>>>(
            (const uint16_t*)d_ws, b1, b2, out);
    } else {
        ngp_mlp_valu<<<dim3(NPTS / PTS_BLK2), dim3(256), 0, stream>>>(
            W1, b1, W2, b2, out);
    }
}

// Round 16
// 1161.427 us; speedup vs baseline: 1.0421x; 1.0003x over previous
//
#include <hip/hip_runtime.h>
#include <cstdint>

// Instant-NGP hash encoding + 2-layer MLP. R15 = proven R10 pipeline
// (encode -> split-bf16 3-MFMA MLP, passed at 1197us) with ONE change:
// encode blocks are level-PAIR-partitioned and XCD-pinned.
//   Block = pair j (levels 2j,2j+1) x 128 points; j = blockIdx%8 -> XCD j
//   under round-robin dispatch. Each XCD's 4MB L2 then serves only 2 levels
//   (<=32MB) instead of all 16 (~200MB) -> L2 retention on fine-level
//   gathers. Lanes (2i,2i+1) write one full 64B line per point (no RMW).
// MLP path byte-identical to R10's (proven).

#define NPTS     524288
#define NLEVELS  16
#define TSIZE    (1u << 19)
#define TMASK    (TSIZE - 1u)
#define APITCH   136      // shorts per LDS row: 128 + 8 pad

typedef float  v4f   __attribute__((ext_vector_type(4)));
typedef float  f32x4 __attribute__((ext_vector_type(4)));
typedef short  s16x8 __attribute__((ext_vector_type(8)));
typedef short  s16x4 __attribute__((ext_vector_type(4)));

// floor(16 * 1.5^l): all fp32-exact integers.
__constant__ float c_res[NLEVELS] = {
    16.f, 24.f, 36.f, 54.f, 81.f, 121.f, 182.f, 273.f,
    410.f, 615.f, 922.f, 1383.f, 2075.f, 3113.f, 4670.f, 7006.f
};

__device__ __forceinline__ uint16_t bf16_rne(float x) {
    uint32_t u = __float_as_uint(x);
    return (uint16_t)((u + 0x7FFFu + ((u >> 16) & 1u)) >> 16);
}
__device__ __forceinline__ void split2(float x, uint16_t& h, uint16_t& l) {
    uint16_t hh = bf16_rne(x);
    float fh = __uint_as_float(((uint32_t)hh) << 16);
    h = hh;
    l = bf16_rne(x - fh);
}

// ---------------- K0: split W1/W2 into hi/lo bf16 in d_ws ----------------
__global__ __launch_bounds__(256)
void split_w(const float* __restrict__ W1, const float* __restrict__ W2,
             uint16_t* __restrict__ ws)
{
    const int i = blockIdx.x * 256 + threadIdx.x;   // 0..49151
    uint16_t h, l;
    if (i < 16384) {
        split2(W1[i], h, l);
        ws[i] = h;
        ws[16384 + i] = l;
    } else {
        const int j = i - 16384;
        split2(W2[j], h, l);
        ws[32768 + j] = h;
        ws[65536 + j] = l;
    }
}

// ---------------- K1: hash encode, level-pair XCD-pinned ----------------
// Block: pair j = blockIdx%8 (levels 2j, 2j+1), points m*128..m*128+127.
// Thread: l = 2j + (t&1), p = m*128 + (t>>1).
// Writes out[p*256 + l*8 .. +7]; lanes (2i,2i+1) cover one 64B line.
__global__ __launch_bounds__(256, 4)
void ngp_encode(const float* __restrict__ z,
                const float* __restrict__ tables,
                float* __restrict__ out)
{
    const int j = blockIdx.x & 7;
    const int m = blockIdx.x >> 3;
    const int t = threadIdx.x;
    const int l = 2 * j + (t & 1);
    const int p = m * 128 + (t >> 1);

    const float z0 = z[p * 3 + 0];
    const float z1 = z[p * 3 + 1];
    const float z2 = z[p * 3 + 2];

    const float res = c_res[l];
    const float xs0 = z0 * res, xs1 = z1 * res, xs2 = z2 * res;
    const float f0 = floorf(xs0), f1 = floorf(xs1), f2 = floorf(xs2);
    const float w0 = xs0 - f0, w1 = xs1 - f1, w2 = xs2 - f2;
    const uint32_t x0 = (uint32_t)f0;
    const uint32_t x1 = (uint32_t)f1;
    const uint32_t x2 = (uint32_t)f2;

    uint32_t idxs[8];
    #pragma unroll
    for (int c = 0; c < 8; ++c) {
        const uint32_t hx = (x0 + ((c >> 2) & 1u)) * 1u;
        const uint32_t hy = (x1 + ((c >> 1) & 1u)) * 2654435761u;
        const uint32_t hz = (x2 + (c & 1u)) * 805459861u;
        idxs[c] = (hx ^ hy ^ hz) & TMASK;
    }

    const float* tab = tables + (size_t)l * (size_t)(TSIZE * 8);

    float a0 = 0.f, a1 = 0.f, a2 = 0.f, a3 = 0.f;
    float a4 = 0.f, a5 = 0.f, a6 = 0.f, a7 = 0.f;

    #pragma unroll
    for (int half = 0; half < 2; ++half) {
        float4 fa[4], fb[4];
        #pragma unroll
        for (int c = 0; c < 4; ++c) {
            const float4* fp = reinterpret_cast<const float4*>(
                tab + ((size_t)idxs[half * 4 + c] << 3));
            fa[c] = fp[0];
            fb[c] = fp[1];
        }
        #pragma unroll
        for (int c = 0; c < 4; ++c) {
            const int cc = half * 4 + c;
            const float cwx = ((cc >> 2) & 1) ? w0 : (1.0f - w0);
            const float cwy = ((cc >> 1) & 1) ? w1 : (1.0f - w1);
            const float cwz = (cc & 1) ? w2 : (1.0f - w2);
            const float cw = (cwx * cwy) * cwz;    // same order as reference prod(-1)
            a0 = fmaf(cw, fa[c].x, a0);
            a1 = fmaf(cw, fa[c].y, a1);
            a2 = fmaf(cw, fa[c].z, a2);
            a3 = fmaf(cw, fa[c].w, a3);
            a4 = fmaf(cw, fb[c].x, a4);
            a5 = fmaf(cw, fb[c].y, a5);
            a6 = fmaf(cw, fb[c].z, a6);
            a7 = fmaf(cw, fb[c].w, a7);
        }
    }

    float* op = out + (size_t)p * 256 + l * 8;
    *reinterpret_cast<float4*>(op)     = make_float4(a0, a1, a2, a3);
    *reinterpret_cast<float4*>(op + 4) = make_float4(a4, a5, a6, a7);
}

// ---------------- K2: split-bf16 MFMA MLP (verbatim from R10, proven) ----------------
__global__ __launch_bounds__(256, 2)
void ngp_mlp_mfma(const uint16_t* __restrict__ ws,
                  const float* __restrict__ b1,
                  const float* __restrict__ b2,
                  float* out)
{
    __shared__ short Ah[64 * APITCH];
    __shared__ short Al[64 * APITCH];
    __shared__ short Hh[64 * APITCH];
    __shared__ short Hl[64 * APITCH];

    const int t     = threadIdx.x;
    const int lane  = t & 63;
    const int w     = t >> 6;
    const int lrow  = lane & 15;
    const int kgrp  = lane >> 4;
    const int pbase = blockIdx.x * 64;

    const uint16_t* W1h = ws;
    const uint16_t* W1l = ws + 16384;
    const uint16_t* W2h = ws + 32768;
    const uint16_t* W2l = ws + 65536;

    // ---- stage enc (fp32, d_out cols 0..127) -> split bf16 LDS ----
    #pragma unroll
    for (int i = 0; i < 8; ++i) {
        const int slot = t + i * 256;
        const int p    = slot >> 5;
        const int c4   = slot & 31;
        const float4 v = *reinterpret_cast<const float4*>(
            out + (size_t)(pbase + p) * 256 + c4 * 4);
        uint16_t h0, l0, h1, l1, h2, l2, h3, l3;
        split2(v.x, h0, l0); split2(v.y, h1, l1);
        split2(v.z, h2, l2); split2(v.w, h3, l3);
        s16x4 sh = { (short)h0, (short)h1, (short)h2, (short)h3 };
        s16x4 sl = { (short)l0, (short)l1, (short)l2, (short)l3 };
        *reinterpret_cast<s16x4*>(&Ah[p * APITCH + c4 * 4]) = sh;
        *reinterpret_cast<s16x4*>(&Al[p * APITCH + c4 * 4]) = sl;
    }
    __syncthreads();

    // ---- layer 1: [64x128] @ W1^T, wave cols = [w*32, w*32+32) ----
    {
        const int nb = w * 32;
        f32x4 acc[4][2];
        #pragma unroll
        for (int mi = 0; mi < 4; ++mi)
            #pragma unroll
            for (int ni = 0; ni < 2; ++ni)
                acc[mi][ni] = (f32x4){ 0.f, 0.f, 0.f, 0.f };

        #pragma unroll
        for (int kc = 0; kc < 4; ++kc) {
            const int koff = kc * 32 + kgrp * 8;
            s16x8 ah[4], al[4];
            #pragma unroll
            for (int mi = 0; mi < 4; ++mi) {
                const int row = mi * 16 + lrow;
                ah[mi] = *reinterpret_cast<const s16x8*>(&Ah[row * APITCH + koff]);
                al[mi] = *reinterpret_cast<const s16x8*>(&Al[row * APITCH + koff]);
            }
            s16x8 bh[2], bl[2];
            #pragma unroll
            for (int ni = 0; ni < 2; ++ni) {
                const int col = nb + ni * 16 + lrow;
                bh[ni] = *reinterpret_cast<const s16x8*>(&W1h[col * 128 + koff]);
                bl[ni] = *reinterpret_cast<const s16x8*>(&W1l[col * 128 + koff]);
            }
            #pragma unroll
            for (int mi = 0; mi < 4; ++mi)
                #pragma unroll
                for (int ni = 0; ni < 2; ++ni) {
                    acc[mi][ni] = __builtin_amdgcn_mfma_f32_16x16x32_bf16(
                        ah[mi], bh[ni], acc[mi][ni], 0, 0, 0);
                    acc[mi][ni] = __builtin_amdgcn_mfma_f32_16x16x32_bf16(
                        ah[mi], bl[ni], acc[mi][ni], 0, 0, 0);
                    acc[mi][ni] = __builtin_amdgcn_mfma_f32_16x16x32_bf16(
                        al[mi], bh[ni], acc[mi][ni], 0, 0, 0);
                }
        }

        // bias + LeakyReLU, split to bf16 hi/lo hidden
        #pragma unroll
        for (int mi = 0; mi < 4; ++mi)
            #pragma unroll
            for (int ni = 0; ni < 2; ++ni) {
                const int col = nb + ni * 16 + lrow;
                const float bj = b1[col];
                #pragma unroll
                for (int r = 0; r < 4; ++r) {
                    const int row = mi * 16 + kgrp * 4 + r;
                    float v = acc[mi][ni][r] + bj;
                    v = (v >= 0.f) ? v : 0.01f * v;
                    uint16_t h, l;
                    split2(v, h, l);
                    Hh[row * APITCH + col] = (short)h;
                    Hl[row * APITCH + col] = (short)l;
                }
            }
    }
    __syncthreads();

    // ---- layer 2: [64x128] @ W2^T, wave cols = [w*64, w*64+64) ----
    #pragma unroll
    for (int pass = 0; pass < 2; ++pass) {
        const int nb = w * 64 + pass * 32;
        f32x4 acc[4][2];
        #pragma unroll
        for (int mi = 0; mi < 4; ++mi)
            #pragma unroll
            for (int ni = 0; ni < 2; ++ni)
                acc[mi][ni] = (f32x4){ 0.f, 0.f, 0.f, 0.f };

        #pragma unroll
        for (int kc = 0; kc < 4; ++kc) {
            const int koff = kc * 32 + kgrp * 8;
            s16x8 ah[4], al[4];
            #pragma unroll
            for (int mi = 0; mi < 4; ++mi) {
                const int row = mi * 16 + lrow;
                ah[mi] = *reinterpret_cast<const s16x8*>(&Hh[row * APITCH + koff]);
                al[mi] = *reinterpret_cast<const s16x8*>(&Hl[row * APITCH + koff]);
            }
            s16x8 bh[2], bl[2];
            #pragma unroll
            for (int ni = 0; ni < 2; ++ni) {
                const int col = nb + ni * 16 + lrow;
                bh[ni] = *reinterpret_cast<const s16x8*>(&W2h[col * 128 + koff]);
                bl[ni] = *reinterpret_cast<const s16x8*>(&W2l[col * 128 + koff]);
            }
            #pragma unroll
            for (int mi = 0; mi < 4; ++mi)
                #pragma unroll
                for (int ni = 0; ni < 2; ++ni) {
                    acc[mi][ni] = __builtin_amdgcn_mfma_f32_16x16x32_bf16(
                        ah[mi], bh[ni], acc[mi][ni], 0, 0, 0);
                    acc[mi][ni] = __builtin_amdgcn_mfma_f32_16x16x32_bf16(
                        ah[mi], bl[ni], acc[mi][ni], 0, 0, 0);
                    acc[mi][ni] = __builtin_amdgcn_mfma_f32_16x16x32_bf16(
                        al[mi], bh[ni], acc[mi][ni], 0, 0, 0);
                }
        }

        #pragma unroll
        for (int mi = 0; mi < 4; ++mi)
            #pragma unroll
            for (int ni = 0; ni < 2; ++ni) {
                const int col = nb + ni * 16 + lrow;
                const float bj = b2[col];
                #pragma unroll
                for (int r = 0; r < 4; ++r) {
                    const int row = mi * 16 + kgrp * 4 + r;
                    __builtin_nontemporal_store(
                        acc[mi][ni][r] + bj,
                        out + (size_t)(pbase + row) * 256 + col);
                }
            }
    }
}

// ---------------- fallback fp32 VALU MLP (known-good) ----------------
#define PTS_BLK2 32
#define PITCH2   132
__global__ __launch_bounds__(256, 4)
void ngp_mlp_valu(const float* __restrict__ W1, const float* __restrict__ b1,
                  const float* __restrict__ W2, const float* __restrict__ b2,
                  float* out)
{
    __shared__ __align__(16) float buf[PTS_BLK2][PITCH2];
    __shared__ __align__(16) float sout[PTS_BLK2][PITCH2];

    const int t     = threadIdx.x;
    const int pbase = blockIdx.x * PTS_BLK2;

    #pragma unroll
    for (int i = 0; i < 4; ++i) {
        const int idx = t + i * 256;
        const int p = idx >> 5, c4 = idx & 31;
        *reinterpret_cast<float4*>(&buf[p][c4 * 4]) =
            *reinterpret_cast<const float4*>(out + (size_t)(pbase + p) * 256 + c4 * 4);
    }
    __syncthreads();

    const int px = t & 15, cy = t >> 4, colb = cy * 8;

    float h0[8], h1[8];
    {
        float a0[8], a1[8];
        #pragma unroll
        for (int j = 0; j < 8; ++j) { a0[j] = 0.f; a1[j] = 0.f; }
        #pragma unroll 2
        for (int k = 0; k < 128; k += 4) {
            const float4 e0 = *reinterpret_cast<const float4*>(&buf[px][k]);
            const float4 e1 = *reinterpret_cast<const float4*>(&buf[px + 16][k]);
            #pragma unroll
            for (int j = 0; j < 8; ++j) {
                const float4 wv = *reinterpret_cast<const float4*>(&W1[(size_t)(colb + j) * 128 + k]);
                a0[j] = fmaf(e0.x, wv.x, a0[j]); a0[j] = fmaf(e0.y, wv.y, a0[j]);
                a0[j] = fmaf(e0.z, wv.z, a0[j]); a0[j] = fmaf(e0.w, wv.w, a0[j]);
                a1[j] = fmaf(e1.x, wv.x, a1[j]); a1[j] = fmaf(e1.y, wv.y, a1[j]);
                a1[j] = fmaf(e1.z, wv.z, a1[j]); a1[j] = fmaf(e1.w, wv.w, a1[j]);
            }
        }
        #pragma unroll
        for (int j = 0; j < 8; ++j) {
            const float bj = b1[colb + j];
            float v0 = a0[j] + bj, v1 = a1[j] + bj;
            h0[j] = (v0 >= 0.f) ? v0 : 0.01f * v0;
            h1[j] = (v1 >= 0.f) ? v1 : 0.01f * v1;
        }
    }
    __syncthreads();
    *reinterpret_cast<float4*>(&buf[px][colb])          = make_float4(h0[0], h0[1], h0[2], h0[3]);
    *reinterpret_cast<float4*>(&buf[px][colb + 4])      = make_float4(h0[4], h0[5], h0[6], h0[7]);
    *reinterpret_cast<float4*>(&buf[px + 16][colb])     = make_float4(h1[0], h1[1], h1[2], h1[3]);
    *reinterpret_cast<float4*>(&buf[px + 16][colb + 4]) = make_float4(h1[4], h1[5], h1[6], h1[7]);
    __syncthreads();

    #pragma unroll
    for (int half = 0; half < 2; ++half) {
        float c0[8], c1[8];
        #pragma unroll
        for (int j = 0; j < 8; ++j) { c0[j] = 0.f; c1[j] = 0.f; }
        const int orow = half * 128 + colb;
        #pragma unroll 2
        for (int k = 0; k < 128; k += 4) {
            const float4 g0 = *reinterpret_cast<const float4*>(&buf[px][k]);
            const float4 g1 = *reinterpret_cast<const float4*>(&buf[px + 16][k]);
            #pragma unroll
            for (int j = 0; j < 8; ++j) {
                const float4 wv = *reinterpret_cast<const float4*>(&W2[(size_t)(orow + j) * 128 + k]);
                c0[j] = fmaf(g0.x, wv.x, c0[j]); c0[j] = fmaf(g0.y, wv.y, c0[j]);
                c0[j] = fmaf(g0.z, wv.z, c0[j]); c0[j] = fmaf(g0.w, wv.w, c0[j]);
                c1[j] = fmaf(g1.x, wv.x, c1[j]); c1[j] = fmaf(g1.y, wv.y, c1[j]);
                c1[j] = fmaf(g1.z, wv.z, c1[j]); c1[j] = fmaf(g1.w, wv.w, c1[j]);
            }
        }
        #pragma unroll
        for (int j = 0; j < 8; ++j) { c0[j] += b2[orow + j]; c1[j] += b2[orow + j]; }
        *reinterpret_cast<float4*>(&sout[px][colb])          = make_float4(c0[0], c0[1], c0[2], c0[3]);
        *reinterpret_cast<float4*>(&sout[px][colb + 4])      = make_float4(c0[4], c0[5], c0[6], c0[7]);
        *reinterpret_cast<float4*>(&sout[px + 16][colb])     = make_float4(c1[0], c1[1], c1[2], c1[3]);
        *reinterpret_cast<float4*>(&sout[px + 16][colb + 4]) = make_float4(c1[4], c1[5], c1[6], c1[7]);
        __syncthreads();
        #pragma unroll
        for (int i = 0; i < 4; ++i) {
            const int idx = t + i * 256;
            const int p = idx >> 5, c4 = idx & 31;
            const float4 v = *reinterpret_cast<const float4*>(&sout[p][c4 * 4]);
            v4f s; s.x = v.x; s.y = v.y; s.z = v.z; s.w = v.w;
            __builtin_nontemporal_store(
                s, reinterpret_cast<v4f*>(out + (size_t)(pbase + p) * 256 + half * 128 + c4 * 4));
        }
        __syncthreads();
    }
}

extern "C" void kernel_launch(void* const* d_in, const int* in_sizes, int n_in,
                              void* d_out, int out_size, void* d_ws, size_t ws_size,
                              hipStream_t stream) {
    (void)in_sizes; (void)n_in; (void)out_size;

    const float* z      = (const float*)d_in[0];
    const float* tables = (const float*)d_in[1];
    const float* W1     = (const float*)d_in[2];
    const float* b1     = (const float*)d_in[3];
    const float* W2     = (const float*)d_in[4];
    const float* b2     = (const float*)d_in[5];
    float* out          = (float*)d_out;

    // encode: 8 pairs x (524288/128) chunks = 32768 blocks; pair = blockIdx%8
    ngp_encode<<<dim3((NPTS / 128) * 8), dim3(256), 0, stream>>>(z, tables, out);

    if (ws_size >= 196608) {
        split_w<<<dim3(192), dim3(256), 0, stream>>>(W1, W2, (uint16_t*)d_ws);
        ngp_mlp_mfma<<<dim3(NPTS / 64), dim3(256), 0, stream>>>(
            (const uint16_t*)d_ws, b1, b2, out);
    } else {
        ngp_mlp_valu<<<dim3(NPTS / PTS_BLK2), dim3(256), 0, stream>>>(
            W1, b1, W2, b2, out);
    }
}

// Round 18
// 935.309 us; speedup vs baseline: 1.2940x; 1.2418x over previous
//
#include <hip/hip_runtime.h>
#include <cstdint>

// Instant-NGP hash encoding + 2-layer MLP. R18: FUSED via fp32-LDS bounce.
// Bisection build: every stage is the PROVEN split-pipeline code with exactly
// one pointer changed.
//   Phase A  = proven ngp_encode body; stores fp32 float4 -> LDS encbuf
//              (instead of global out).
//   Staging  = proven ngp_mlp_mfma staging loop; float4 source = encbuf
//              (instead of out).
//   L1/L2    = proven ngp_mlp_mfma verbatim (separate Hh/Hl).
// encbuf (33.8KB, dead after staging) shares a byte-union with Hh/Hl
// (34.8KB, born after layer 1): A-write | sync | stage-read | sync |
// L1 (Hh/Hl over dead encbuf) | sync | L2.  LDS = 68KB -> 2 blocks/CU.

#define NPTS     524288
#define NLEVELS  16
#define TSIZE    (1u << 19)
#define TMASK    (TSIZE - 1u)
#define APITCH   136      // shorts per LDS row: 128 + 8 pad
#define EPITCH   132      // floats per encbuf row: 128 + 4 pad

typedef float  v4f   __attribute__((ext_vector_type(4)));
typedef float  f32x4 __attribute__((ext_vector_type(4)));
typedef short  s16x8 __attribute__((ext_vector_type(8)));
typedef short  s16x4 __attribute__((ext_vector_type(4)));

// floor(16 * 1.5^l): all fp32-exact integers.
__constant__ float c_res[NLEVELS] = {
    16.f, 24.f, 36.f, 54.f, 81.f, 121.f, 182.f, 273.f,
    410.f, 615.f, 922.f, 1383.f, 2075.f, 3113.f, 4670.f, 7006.f
};

__device__ __forceinline__ uint16_t bf16_rne(float x) {
    uint32_t u = __float_as_uint(x);
    return (uint16_t)((u + 0x7FFFu + ((u >> 16) & 1u)) >> 16);
}
__device__ __forceinline__ void split2(float x, uint16_t& h, uint16_t& l) {
    uint16_t hh = bf16_rne(x);
    float fh = __uint_as_float(((uint32_t)hh) << 16);
    h = hh;
    l = bf16_rne(x - fh);
}

// ---------------- K0: split W1/W2 into hi/lo bf16 in d_ws ----------------
__global__ __launch_bounds__(256)
void split_w(const float* __restrict__ W1, const float* __restrict__ W2,
             uint16_t* __restrict__ ws)
{
    const int i = blockIdx.x * 256 + threadIdx.x;   // 0..49151
    uint16_t h, l;
    if (i < 16384) {
        split2(W1[i], h, l);
        ws[i] = h;
        ws[16384 + i] = l;
    } else {
        const int j = i - 16384;
        split2(W2[j], h, l);
        ws[32768 + j] = h;
        ws[65536 + j] = l;
    }
}

// ---------------- FUSED: encode -> LDS fp32 -> proven staging + MFMA MLP ----------------
__global__ __launch_bounds__(256, 2)
void ngp_fused(const float* __restrict__ z,
               const float* __restrict__ tables,
               const uint16_t* __restrict__ ws,
               const float* __restrict__ b1,
               const float* __restrict__ b2,
               float* __restrict__ out)
{
    __shared__ __align__(16) short Ah[64 * APITCH];          // enc hi (bf16)
    __shared__ __align__(16) short Al[64 * APITCH];          // enc lo (bf16)
    // union: encbuf (fp32 enc, Phase A..staging) / Hh+Hl (hidden, L1..L2)
    __shared__ __align__(16) unsigned char ubuf[2 * 64 * APITCH * 2];
    float (*encbuf)[EPITCH] = reinterpret_cast<float (*)[EPITCH]>(ubuf);
    short* Hh = reinterpret_cast<short*>(ubuf);
    short* Hl = reinterpret_cast<short*>(ubuf + 64 * APITCH * 2);

    const int t     = threadIdx.x;
    const int lane  = t & 63;
    const int w     = t >> 6;
    const int lrow  = lane & 15;
    const int kgrp  = lane >> 4;
    const int pbase = blockIdx.x * 64;

    const uint16_t* W1h = ws;
    const uint16_t* W1l = ws + 16384;
    const uint16_t* W2h = ws + 32768;
    const uint16_t* W2l = ws + 65536;

    // ===== Phase A: proven encode body; store fp32 -> encbuf =====
    {
        const int lv = t & 15;          // level, fixed per thread
        const int pr = t >> 4;          // point row base
        const float res = c_res[lv];
        const float* tab = tables + (size_t)lv * (size_t)(TSIZE * 8);

        #pragma unroll 1
        for (int ti = 0; ti < 4; ++ti) {
            const int p  = pr + 16 * ti;
            const int gp = pbase + p;

            const float z0 = z[gp * 3 + 0];
            const float z1 = z[gp * 3 + 1];
            const float z2 = z[gp * 3 + 2];

            const float xs0 = z0 * res, xs1 = z1 * res, xs2 = z2 * res;
            const float f0 = floorf(xs0), f1 = floorf(xs1), f2 = floorf(xs2);
            const float w0 = xs0 - f0, w1 = xs1 - f1, w2 = xs2 - f2;
            const uint32_t x0 = (uint32_t)f0;
            const uint32_t x1 = (uint32_t)f1;
            const uint32_t x2 = (uint32_t)f2;

            uint32_t idxs[8];
            #pragma unroll
            for (int c = 0; c < 8; ++c) {
                const uint32_t hx = (x0 + ((c >> 2) & 1u)) * 1u;
                const uint32_t hy = (x1 + ((c >> 1) & 1u)) * 2654435761u;
                const uint32_t hz = (x2 + (c & 1u)) * 805459861u;
                idxs[c] = (hx ^ hy ^ hz) & TMASK;
            }

            float a0 = 0.f, a1 = 0.f, a2 = 0.f, a3 = 0.f;
            float a4 = 0.f, a5 = 0.f, a6 = 0.f, a7 = 0.f;

            #pragma unroll
            for (int half = 0; half < 2; ++half) {
                float4 fa[4], fb[4];
                #pragma unroll
                for (int c = 0; c < 4; ++c) {
                    const float4* fp = reinterpret_cast<const float4*>(
                        tab + ((size_t)idxs[half * 4 + c] << 3));
                    fa[c] = fp[0];
                    fb[c] = fp[1];
                }
                #pragma unroll
                for (int c = 0; c < 4; ++c) {
                    const int cc = half * 4 + c;
                    const float cwx = ((cc >> 2) & 1) ? w0 : (1.0f - w0);
                    const float cwy = ((cc >> 1) & 1) ? w1 : (1.0f - w1);
                    const float cwz = (cc & 1) ? w2 : (1.0f - w2);
                    const float cw = (cwx * cwy) * cwz;   // ref prod(-1) order
                    a0 = fmaf(cw, fa[c].x, a0);
                    a1 = fmaf(cw, fa[c].y, a1);
                    a2 = fmaf(cw, fa[c].z, a2);
                    a3 = fmaf(cw, fa[c].w, a3);
                    a4 = fmaf(cw, fb[c].x, a4);
                    a5 = fmaf(cw, fb[c].y, a5);
                    a6 = fmaf(cw, fb[c].z, a6);
                    a7 = fmaf(cw, fb[c].w, a7);
                }
            }

            // identical to proven encode's store, destination = LDS encbuf
            float* op = &encbuf[p][lv * 8];
            *reinterpret_cast<float4*>(op)     = make_float4(a0, a1, a2, a3);
            *reinterpret_cast<float4*>(op + 4) = make_float4(a4, a5, a6, a7);
        }
    }
    __syncthreads();

    // ===== staging (proven K2 loop; source = encbuf instead of out) =====
    #pragma unroll
    for (int i = 0; i < 8; ++i) {
        const int slot = t + i * 256;
        const int p    = slot >> 5;
        const int c4   = slot & 31;
        const float4 v = *reinterpret_cast<const float4*>(&encbuf[p][c4 * 4]);
        uint16_t h0, l0, h1, l1, h2, l2, h3, l3;
        split2(v.x, h0, l0); split2(v.y, h1, l1);
        split2(v.z, h2, l2); split2(v.w, h3, l3);
        s16x4 sh = { (short)h0, (short)h1, (short)h2, (short)h3 };
        s16x4 sl = { (short)l0, (short)l1, (short)l2, (short)l3 };
        *reinterpret_cast<s16x4*>(&Ah[p * APITCH + c4 * 4]) = sh;
        *reinterpret_cast<s16x4*>(&Al[p * APITCH + c4 * 4]) = sl;
    }
    __syncthreads();   // all encbuf reads complete -> Hh/Hl may overwrite it

    // ===== layer 1 (proven K2): [64x128] @ W1^T, wave cols [w*32, +32) =====
    {
        const int nb = w * 32;
        f32x4 acc[4][2];
        #pragma unroll
        for (int mi = 0; mi < 4; ++mi)
            #pragma unroll
            for (int ni = 0; ni < 2; ++ni)
                acc[mi][ni] = (f32x4){ 0.f, 0.f, 0.f, 0.f };

        #pragma unroll
        for (int kc = 0; kc < 4; ++kc) {
            const int koff = kc * 32 + kgrp * 8;
            s16x8 ah[4], al[4];
            #pragma unroll
            for (int mi = 0; mi < 4; ++mi) {
                const int row = mi * 16 + lrow;
                ah[mi] = *reinterpret_cast<const s16x8*>(&Ah[row * APITCH + koff]);
                al[mi] = *reinterpret_cast<const s16x8*>(&Al[row * APITCH + koff]);
            }
            s16x8 bh[2], bl[2];
            #pragma unroll
            for (int ni = 0; ni < 2; ++ni) {
                const int col = nb + ni * 16 + lrow;
                bh[ni] = *reinterpret_cast<const s16x8*>(&W1h[col * 128 + koff]);
                bl[ni] = *reinterpret_cast<const s16x8*>(&W1l[col * 128 + koff]);
            }
            #pragma unroll
            for (int mi = 0; mi < 4; ++mi)
                #pragma unroll
                for (int ni = 0; ni < 2; ++ni) {
                    acc[mi][ni] = __builtin_amdgcn_mfma_f32_16x16x32_bf16(
                        ah[mi], bh[ni], acc[mi][ni], 0, 0, 0);
                    acc[mi][ni] = __builtin_amdgcn_mfma_f32_16x16x32_bf16(
                        ah[mi], bl[ni], acc[mi][ni], 0, 0, 0);
                    acc[mi][ni] = __builtin_amdgcn_mfma_f32_16x16x32_bf16(
                        al[mi], bh[ni], acc[mi][ni], 0, 0, 0);
                }
        }

        // bias + LeakyReLU, split to Hh/Hl (over dead encbuf space)
        #pragma unroll
        for (int mi = 0; mi < 4; ++mi)
            #pragma unroll
            for (int ni = 0; ni < 2; ++ni) {
                const int col = nb + ni * 16 + lrow;
                const float bj = b1[col];
                #pragma unroll
                for (int r = 0; r < 4; ++r) {
                    const int row = mi * 16 + kgrp * 4 + r;
                    float v = acc[mi][ni][r] + bj;
                    v = (v >= 0.f) ? v : 0.01f * v;
                    uint16_t h, l;
                    split2(v, h, l);
                    Hh[row * APITCH + col] = (short)h;
                    Hl[row * APITCH + col] = (short)l;
                }
            }
    }
    __syncthreads();

    // ===== layer 2 (proven K2): [64x128] @ W2^T, wave cols [w*64, +64) =====
    #pragma unroll
    for (int pass = 0; pass < 2; ++pass) {
        const int nb = w * 64 + pass * 32;
        f32x4 acc[4][2];
        #pragma unroll
        for (int mi = 0; mi < 4; ++mi)
            #pragma unroll
            for (int ni = 0; ni < 2; ++ni)
                acc[mi][ni] = (f32x4){ 0.f, 0.f, 0.f, 0.f };

        #pragma unroll
        for (int kc = 0; kc < 4; ++kc) {
            const int koff = kc * 32 + kgrp * 8;
            s16x8 ah[4], al[4];
            #pragma unroll
            for (int mi = 0; mi < 4; ++mi) {
                const int row = mi * 16 + lrow;
                ah[mi] = *reinterpret_cast<const s16x8*>(&Hh[row * APITCH + koff]);
                al[mi] = *reinterpret_cast<const s16x8*>(&Hl[row * APITCH + koff]);
            }
            s16x8 bh[2], bl[2];
            #pragma unroll
            for (int ni = 0; ni < 2; ++ni) {
                const int col = nb + ni * 16 + lrow;
                bh[ni] = *reinterpret_cast<const s16x8*>(&W2h[col * 128 + koff]);
                bl[ni] = *reinterpret_cast<const s16x8*>(&W2l[col * 128 + koff]);
            }
            #pragma unroll
            for (int mi = 0; mi < 4; ++mi)
                #pragma unroll
                for (int ni = 0; ni < 2; ++ni) {
                    acc[mi][ni] = __builtin_amdgcn_mfma_f32_16x16x32_bf16(
                        ah[mi], bh[ni], acc[mi][ni], 0, 0, 0);
                    acc[mi][ni] = __builtin_amdgcn_mfma_f32_16x16x32_bf16(
                        ah[mi], bl[ni], acc[mi][ni], 0, 0, 0);
                    acc[mi][ni] = __builtin_amdgcn_mfma_f32_16x16x32_bf16(
                        al[mi], bh[ni], acc[mi][ni], 0, 0, 0);
                }
        }

        #pragma unroll
        for (int mi = 0; mi < 4; ++mi)
            #pragma unroll
            for (int ni = 0; ni < 2; ++ni) {
                const int col = nb + ni * 16 + lrow;
                const float bj = b2[col];
                #pragma unroll
                for (int r = 0; r < 4; ++r) {
                    const int row = mi * 16 + kgrp * 4 + r;
                    __builtin_nontemporal_store(
                        acc[mi][ni][r] + bj,
                        out + (size_t)(pbase + row) * 256 + col);
                }
            }
    }
}

// ================= fallback (proven): encode + VALU MLP =================
__global__ __launch_bounds__(256, 4)
void ngp_encode(const float* __restrict__ z,
                const float* __restrict__ tables,
                float* __restrict__ out)
{
    const int id = blockIdx.x * 256 + threadIdx.x;
    const int p  = id >> 4;
    const int l  = id & 15;

    const float z0 = z[p * 3 + 0];
    const float z1 = z[p * 3 + 1];
    const float z2 = z[p * 3 + 2];

    const float res = c_res[l];
    const float xs0 = z0 * res, xs1 = z1 * res, xs2 = z2 * res;
    const float f0 = floorf(xs0), f1 = floorf(xs1), f2 = floorf(xs2);
    const float w0 = xs0 - f0, w1 = xs1 - f1, w2 = xs2 - f2;
    const uint32_t x0 = (uint32_t)f0;
    const uint32_t x1 = (uint32_t)f1;
    const uint32_t x2 = (uint32_t)f2;

    uint32_t idxs[8];
    #pragma unroll
    for (int c = 0; c < 8; ++c) {
        const uint32_t hx = (x0 + ((c >> 2) & 1u)) * 1u;
        const uint32_t hy = (x1 + ((c >> 1) & 1u)) * 2654435761u;
        const uint32_t hz = (x2 + (c & 1u)) * 805459861u;
        idxs[c] = (hx ^ hy ^ hz) & TMASK;
    }

    const float* tab = tables + (size_t)l * (size_t)(TSIZE * 8);

    float a0 = 0.f, a1 = 0.f, a2 = 0.f, a3 = 0.f;
    float a4 = 0.f, a5 = 0.f, a6 = 0.f, a7 = 0.f;

    #pragma unroll
    for (int half = 0; half < 2; ++half) {
        float4 fa[4], fb[4];
        #pragma unroll
        for (int c = 0; c < 4; ++c) {
            const float4* fp = reinterpret_cast<const float4*>(
                tab + ((size_t)idxs[half * 4 + c] << 3));
            fa[c] = fp[0];
            fb[c] = fp[1];
        }
        #pragma unroll
        for (int c = 0; c < 4; ++c) {
            const int cc = half * 4 + c;
            const float cwx = ((cc >> 2) & 1) ? w0 : (1.0f - w0);
            const float cwy = ((cc >> 1) & 1) ? w1 : (1.0f - w1);
            const float cwz = (cc & 1) ? w2 : (1.0f - w2);
            const float cw = (cwx * cwy) * cwz;
            a0 = fmaf(cw, fa[c].x, a0);
            a1 = fmaf(cw, fa[c].y, a1);
            a2 = fmaf(cw, fa[c].z, a2);
            a3 = fmaf(cw, fa[c].w, a3);
            a4 = fmaf(cw, fb[c].x, a4);
            a5 = fmaf(cw, fb[c].y, a5);
            a6 = fmaf(cw, fb[c].z, a6);
            a7 = fmaf(cw, fb[c].w, a7);
        }
    }

    float* op = out + (size_t)p * 256 + l * 8;
    *reinterpret_cast<float4*>(op)     = make_float4(a0, a1, a2, a3);
    *reinterpret_cast<float4*>(op + 4) = make_float4(a4, a5, a6, a7);
}

#define PTS_BLK2 32
#define PITCH2   132
__global__ __launch_bounds__(256, 4)
void ngp_mlp_valu(const float* __restrict__ W1, const float* __restrict__ b1,
                  const float* __restrict__ W2, const float* __restrict__ b2,
                  float* out)
{
    __shared__ __align__(16) float buf[PTS_BLK2][PITCH2];
    __shared__ __align__(16) float sout[PTS_BLK2][PITCH2];

    const int t     = threadIdx.x;
    const int pbase = blockIdx.x * PTS_BLK2;

    #pragma unroll
    for (int i = 0; i < 4; ++i) {
        const int idx = t + i * 256;
        const int p = idx >> 5, c4 = idx & 31;
        *reinterpret_cast<float4*>(&buf[p][c4 * 4]) =
            *reinterpret_cast<const float4*>(out + (size_t)(pbase + p) * 256 + c4 * 4);
    }
    __syncthreads();

    const int px = t & 15, cy = t >> 4, colb = cy * 8;

    float h0[8], h1[8];
    {
        float a0[8], a1[8];
        #pragma unroll
        for (int j = 0; j < 8; ++j) { a0[j] = 0.f; a1[j] = 0.f; }
        #pragma unroll 2
        for (int k = 0; k < 128; k += 4) {
            const float4 e0 = *reinterpret_cast<const float4*>(&buf[px][k]);
            const float4 e1 = *reinterpret_cast<const float4*>(&buf[px + 16][k]);
            #pragma unroll
            for (int j = 0; j < 8; ++j) {
                const float4 wv = *reinterpret_cast<const float4*>(&W1[(size_t)(colb + j) * 128 + k]);
                a0[j] = fmaf(e0.x, wv.x, a0[j]); a0[j] = fmaf(e0.y, wv.y, a0[j]);
                a0[j] = fmaf(e0.z, wv.z, a0[j]); a0[j] = fmaf(e0.w, wv.w, a0[j]);
                a1[j] = fmaf(e1.x, wv.x, a1[j]); a1[j] = fmaf(e1.y, wv.y, a1[j]);
                a1[j] = fmaf(e1.z, wv.z, a1[j]); a1[j] = fmaf(e1.w, wv.w, a1[j]);
            }
        }
        #pragma unroll
        for (int j = 0; j < 8; ++j) {
            const float bj = b1[colb + j];
            float v0 = a0[j] + bj, v1 = a1[j] + bj;
            h0[j] = (v0 >= 0.f) ? v0 : 0.01f * v0;
            h1[j] = (v1 >= 0.f) ? v1 : 0.01f * v1;
        }
    }
    __syncthreads();
    *reinterpret_cast<float4*>(&buf[px][colb])          = make_float4(h0[0], h0[1], h0[2], h0[3]);
    *reinterpret_cast<float4*>(&buf[px][colb + 4])      = make_float4(h0[4], h0[5], h0[6], h0[7]);
    *reinterpret_cast<float4*>(&buf[px + 16][colb])     = make_float4(h1[0], h1[1], h1[2], h1[3]);
    *reinterpret_cast<float4*>(&buf[px + 16][colb + 4]) = make_float4(h1[4], h1[5], h1[6], h1[7]);
    __syncthreads();

    #pragma unroll
    for (int half = 0; half < 2; ++half) {
        float c0[8], c1[8];
        #pragma unroll
        for (int j = 0; j < 8; ++j) { c0[j] = 0.f; c1[j] = 0.f; }
        const int orow = half * 128 + colb;
        #pragma unroll 2
        for (int k = 0; k < 128; k += 4) {
            const float4 g0 = *reinterpret_cast<const float4*>(&buf[px][k]);
            const float4 g1 = *reinterpret_cast<const float4*>(&buf[px + 16][k]);
            #pragma unroll
            for (int j = 0; j < 8; ++j) {
                const float4 wv = *reinterpret_cast<const float4*>(&W2[(size_t)(orow + j) * 128 + k]);
                c0[j] = fmaf(g0.x, wv.x, c0[j]); c0[j] = fmaf(g0.y, wv.y, c0[j]);
                c0[j] = fmaf(g0.z, wv.z, c0[j]); c0[j] = fmaf(g0.w, wv.w, c0[j]);
                c1[j] = fmaf(g1.x, wv.x, c1[j]); c1[j] = fmaf(g1.y, wv.y, c1[j]);
                c1[j] = fmaf(g1.z, wv.z, c1[j]); c1[j] = fmaf(g1.w, wv.w, c1[j]);
            }
        }
        #pragma unroll
        for (int j = 0; j < 8; ++j) { c0[j] += b2[orow + j]; c1[j] += b2[orow + j]; }
        *reinterpret_cast<float4*>(&sout[px][colb])          = make_float4(c0[0], c0[1], c0[2], c0[3]);
        *reinterpret_cast<float4*>(&sout[px][colb + 4])      = make_float4(c0[4], c0[5], c0[6], c0[7]);
        *reinterpret_cast<float4*>(&sout[px + 16][colb])     = make_float4(c1[0], c1[1], c1[2], c1[3]);
        *reinterpret_cast<float4*>(&sout[px + 16][colb + 4]) = make_float4(c1[4], c1[5], c1[6], c1[7]);
        __syncthreads();
        #pragma unroll
        for (int i = 0; i < 4; ++i) {
            const int idx = t + i * 256;
            const int p = idx >> 5, c4 = idx & 31;
            const float4 v = *reinterpret_cast<const float4*>(&sout[p][c4 * 4]);
            v4f s; s.x = v.x; s.y = v.y; s.z = v.z; s.w = v.w;
            __builtin_nontemporal_store(
                s, reinterpret_cast<v4f*>(out + (size_t)(pbase + p) * 256 + half * 128 + c4 * 4));
        }
        __syncthreads();
    }
}

extern "C" void kernel_launch(void* const* d_in, const int* in_sizes, int n_in,
                              void* d_out, int out_size, void* d_ws, size_t ws_size,
                              hipStream_t stream) {
    (void)in_sizes; (void)n_in; (void)out_size;

    const float* z      = (const float*)d_in[0];
    const float* tables = (const float*)d_in[1];
    const float* W1     = (const float*)d_in[2];
    const float* b1     = (const float*)d_in[3];
    const float* W2     = (const float*)d_in[4];
    const float* b2     = (const float*)d_in[5];
    float* out          = (float*)d_out;

    if (ws_size >= 196608) {
        split_w<<<dim3(192), dim3(256), 0, stream>>>(W1, W2, (uint16_t*)d_ws);
        ngp_fused<<<dim3(NPTS / 64), dim3(256), 0, stream>>>(
            z, tables, (const uint16_t*)d_ws, b1, b2, out);
    } else {
        ngp_encode<<<dim3((NPTS * 16) / 256), dim3(256), 0, stream>>>(z, tables, out);
        ngp_mlp_valu<<<dim3(NPTS / PTS_BLK2), dim3(256), 0, stream>>>(
            W1, b1, W2, b2, out);
    }
}